// Round 2
// baseline (4218.801 us; speedup 1.0000x reference)
//
#include <hip/hip_runtime.h>

#define Tn 1024
#define Bn 64
#define In_ 64
#define Hn 512
#define On 64
#define NG 8     // batch groups (8 batches each)
#define MB 8     // batches per group
#define NJ 16    // j-slice blocks per group
#define NS 32    // j columns per block
#define DTC 0.5f

typedef __attribute__((ext_vector_type(8))) short short8;   // bf16x8 MFMA frag
typedef __attribute__((ext_vector_type(4))) float floatx4;  // MFMA C frag

__device__ __forceinline__ float bf2f(unsigned short u){
  union{unsigned int i; float f;} v; v.i = ((unsigned int)u)<<16; return v.f;
}
__device__ __forceinline__ unsigned short f2bf(float f){   // RNE
  union{float f; unsigned int i;} v; v.f=f;
  unsigned int x=v.i;
  return (unsigned short)((x + 0x7fffu + ((x>>16)&1u))>>16);
}
// split fp32[8] -> bf16 hi + bf16 lo (residual); bf16 exp range = fp32, no denorm risk
__device__ __forceinline__ void split8(const float* p, short8& hi, short8& lo){
  #pragma unroll
  for (int e = 0; e < 8; e++){
    float x = p[e];
    unsigned short h = f2bf(x);
    hi[e] = (short)h;
    lo[e] = (short)f2bf(x - bf2f(h));
  }
}

__global__ void zero_flags(unsigned int* f, int n){
  int i = blockIdx.x*256 + threadIdx.x;
  if (i < n) f[i] = 0u;
}

// Persistent scan: 128 blocks = 8 batch-groups x 16 j-slices. wrec (hi+lo bf16)
// register-resident all 1024 steps. h exchanged via global (hi+lo bf16) with
// per-step agent-scope flag counters.
__global__ __launch_bounds__(256,1) void rnn_scan(
    const float* __restrict__ inp,   // [B,T,I] fp32
    const float* __restrict__ wi,    // [I,H]
    const float* __restrict__ wrec,  // [H,H]
    const float* __restrict__ brec,  // [H]
    const float* __restrict__ h0,    // [H]
    unsigned short* __restrict__ hs, // ws [B,T,H] bf16
    unsigned short* __restrict__ Hhi,// ws [2][B][H] bf16
    unsigned short* __restrict__ Hlo,// ws [2][B][H] bf16
    unsigned int*  __restrict__ flags)// ws [T][NG]
{
  const int tid  = threadIdx.x;
  const int bid  = blockIdx.x;
  const int g    = bid & (NG-1);
  const int jb   = bid >> 3;
  const int wv   = tid >> 6;
  const int lane = tid & 63;
  const int col  = lane & 15;
  const int quad = lane >> 4;

  __shared__ __align__(16) unsigned short hAhi[16][520];
  __shared__ __align__(16) unsigned short hAlo[16][520];
  __shared__ __align__(16) float red[16][32][4];

  for (int idx = tid; idx < 16*520; idx += 256){
    int r = idx/520, c = idx - r*520;
    hAhi[r][c] = 0; hAlo[r][c] = 0;
  }
  __syncthreads();
  for (int idx = tid; idx < 8*512; idx += 256){
    int r = idx >> 9, c = idx & 511;
    float x = h0[c];
    unsigned short h = f2bf(x);
    hAhi[r][c] = h;
    hAlo[r][c] = f2bf(x - bf2f(h));
  }

  // wrec B-frags (hi+lo): lane holds B[k][j]=wrec[j][k], j=jb*32+nt*16+col, k=wv*128+kk*32+quad*8
  short8 bwh[4][2], bwl[4][2];
  #pragma unroll
  for (int kk = 0; kk < 4; kk++)
    #pragma unroll
    for (int nt = 0; nt < 2; nt++){
      int j = jb*NS + nt*16 + col;
      int k = wv*128 + kk*32 + quad*8;
      split8(wrec + (size_t)j*Hn + k, bwh[kk][nt], bwl[kk][nt]);
    }
  // wave0: wi B-frags (hi+lo), per-lane gather once
  short8 wih[2][2], wil[2][2];
  if (wv == 0){
    #pragma unroll
    for (int kk = 0; kk < 2; kk++)
      #pragma unroll
      for (int nt = 0; nt < 2; nt++){
        int j = jb*NS + nt*16 + col;
        float tmp[8];
        #pragma unroll
        for (int e = 0; e < 8; e++) tmp[e] = wi[(size_t)(kk*32 + quad*8 + e)*Hn + j];
        split8(tmp, wih[kk][nt], wil[kk][nt]);
      }
  }
  const int eb = tid >> 5;
  const int ej = tid & 31;
  const float brec_e = brec[jb*NS + ej];
  const int bglob = g*MB + eb;
  const int inrow = g*MB + (col & 7);   // A rows 8..15 duplicate; their C rows ignored

  __syncthreads();

  for (int t = 0; t < Tn; t++){
    short8 aih[2], ail[2];
    if (wv == 0){
      #pragma unroll
      for (int kk = 0; kk < 2; kk++)
        split8(inp + ((size_t)inrow*Tn + t)*In_ + kk*32 + quad*8, aih[kk], ail[kk]);
    }
    if (t > 0){
      if (tid == 0){
        while (__hip_atomic_load(&flags[(t-1)*NG + g], __ATOMIC_RELAXED,
                                 __HIP_MEMORY_SCOPE_AGENT) < (unsigned)NJ)
          __builtin_amdgcn_s_sleep(2);
        __builtin_amdgcn_fence(__ATOMIC_ACQUIRE, "agent");  // inv L1+L2 post-observation
      }
      __syncthreads();
      const unsigned short* shi = Hhi + ((size_t)(t&1)*Bn + g*MB)*Hn;
      const unsigned short* slo = Hlo + ((size_t)(t&1)*Bn + g*MB)*Hn;
      for (int c2 = tid; c2 < 512; c2 += 256){
        int r = c2 >> 6, cc = (c2 & 63)*8;
        *(short8*)&hAhi[r][cc] = *(const short8*)(shi + r*Hn + cc);
        *(short8*)&hAlo[r][cc] = *(const short8*)(slo + r*Hn + cc);
      }
      __syncthreads();
    }

    // pre[b,j] partial over this wave's K-quarter; hi/lo cross terms (drop lo*lo)
    floatx4 acc[2] = {{0.f,0.f,0.f,0.f},{0.f,0.f,0.f,0.f}};
    #pragma unroll
    for (int kk = 0; kk < 4; kk++){
      int k = wv*128 + kk*32 + quad*8;
      short8 ahi = *(const short8*)&hAhi[col][k];
      short8 alo = *(const short8*)&hAlo[col][k];
      #pragma unroll
      for (int nt = 0; nt < 2; nt++){
        acc[nt] = __builtin_amdgcn_mfma_f32_16x16x32_bf16(ahi, bwh[kk][nt], acc[nt], 0,0,0);
        acc[nt] = __builtin_amdgcn_mfma_f32_16x16x32_bf16(ahi, bwl[kk][nt], acc[nt], 0,0,0);
        acc[nt] = __builtin_amdgcn_mfma_f32_16x16x32_bf16(alo, bwh[kk][nt], acc[nt], 0,0,0);
      }
    }
    if (wv == 0){  // fold xproj = input@wi
      #pragma unroll
      for (int kk = 0; kk < 2; kk++)
        #pragma unroll
        for (int nt = 0; nt < 2; nt++){
          acc[nt] = __builtin_amdgcn_mfma_f32_16x16x32_bf16(aih[kk], wih[kk][nt], acc[nt], 0,0,0);
          acc[nt] = __builtin_amdgcn_mfma_f32_16x16x32_bf16(aih[kk], wil[kk][nt], acc[nt], 0,0,0);
          acc[nt] = __builtin_amdgcn_mfma_f32_16x16x32_bf16(ail[kk], wih[kk][nt], acc[nt], 0,0,0);
        }
    }
    #pragma unroll
    for (int nt = 0; nt < 2; nt++)
      #pragma unroll
      for (int r = 0; r < 4; r++)
        red[quad*4 + r][nt*16 + col][wv] = acc[nt][r];
    __syncthreads();

    {
      floatx4 p = *(const floatx4*)red[eb][ej];
      float pre = p[0] + p[1] + p[2] + p[3] + brec_e;
      float e2x = __expf(2.0f*pre);
      float rec = 1.0f - 2.0f/(e2x + 1.0f);   // tanh, robust at +-inf
      int j = jb*NS + ej;
      float hprev = bf2f(hAhi[eb][j]) + bf2f(hAlo[eb][j]);
      float hnew = (1.0f - DTC)*hprev + DTC*rec;
      unsigned short hi = f2bf(hnew);
      unsigned short lo = f2bf(hnew - bf2f(hi));
      int wb = (t+1) & 1;
      Hhi[((size_t)wb*Bn + bglob)*Hn + j] = hi;
      Hlo[((size_t)wb*Bn + bglob)*Hn + j] = lo;
      hs[((size_t)bglob*Tn + t)*Hn + j] = hi;
    }
    __syncthreads();  // drains each wave's stores to L2 before release
    if (tid == 0 && t < Tn-1){
      __hip_atomic_fetch_add(&flags[t*NG + g], 1u, __ATOMIC_RELEASE,
                             __HIP_MEMORY_SCOPE_AGENT);
    }
  }
}

// out[bt,o] = sum_h hs[bt,h]*wo[h,o]; fp32 out, wo in hi+lo bf16
__global__ __launch_bounds__(256,1) void out_gemm(
    const unsigned short* __restrict__ hs,
    const float* __restrict__ wo,
    float* __restrict__ out)
{
  const int tid = threadIdx.x, bid = blockIdx.x;
  const int wv = tid >> 6, lane = tid & 63, col = lane & 15, quad = lane >> 4;
  const int m0 = bid*64;
  __shared__ __align__(16) unsigned short hsA[64][520];

  for (int c = tid; c < 64*64; c += 256){
    int r = c >> 6, cc = (c & 63)*8;
    *(short8*)&hsA[r][cc] = *(const short8*)(hs + (size_t)(m0 + r)*Hn + cc);
  }
  short8 boh[16], bol[16];
  #pragma unroll
  for (int kk = 0; kk < 16; kk++){
    float tmp[8];
    #pragma unroll
    for (int e = 0; e < 8; e++) tmp[e] = wo[(size_t)(kk*32 + quad*8 + e)*On + wv*16 + col];
    split8(tmp, boh[kk], bol[kk]);
  }
  __syncthreads();

  floatx4 acc[4] = {{0.f,0.f,0.f,0.f},{0.f,0.f,0.f,0.f},{0.f,0.f,0.f,0.f},{0.f,0.f,0.f,0.f}};
  #pragma unroll
  for (int kk = 0; kk < 16; kk++){
    int k = kk*32 + quad*8;
    #pragma unroll
    for (int ms = 0; ms < 4; ms++){
      short8 a = *(const short8*)&hsA[ms*16 + col][k];
      acc[ms] = __builtin_amdgcn_mfma_f32_16x16x32_bf16(a, boh[kk], acc[ms], 0,0,0);
      acc[ms] = __builtin_amdgcn_mfma_f32_16x16x32_bf16(a, bol[kk], acc[ms], 0,0,0);
    }
  }
  #pragma unroll
  for (int ms = 0; ms < 4; ms++)
    #pragma unroll
    for (int r = 0; r < 4; r++){
      int m = m0 + ms*16 + quad*4 + r;
      out[(size_t)m*On + wv*16 + col] = acc[ms][r];
    }
}

extern "C" void kernel_launch(void* const* d_in, const int* in_sizes, int n_in,
                              void* d_out, int out_size, void* d_ws, size_t ws_size,
                              hipStream_t stream){
  const float* inp  = (const float*)d_in[0];
  const float* wi   = (const float*)d_in[1];
  const float* wrec = (const float*)d_in[2];
  const float* wo   = (const float*)d_in[3];
  const float* brec = (const float*)d_in[4];
  const float* h0   = (const float*)d_in[5];
  float* out = (float*)d_out;

  char* ws = (char*)d_ws;
  unsigned short* hs  = (unsigned short*)ws;                       // 64 MB
  size_t off = (size_t)Bn*Tn*Hn*2;
  unsigned short* Hhi = (unsigned short*)(ws + off); off += (size_t)2*Bn*Hn*2;
  unsigned short* Hlo = (unsigned short*)(ws + off); off += (size_t)2*Bn*Hn*2;
  unsigned int*  flags = (unsigned int*)(ws + off);                // 32 KB

  zero_flags<<<(Tn*NG + 255)/256, 256, 0, stream>>>(flags, Tn*NG);
  rnn_scan<<<NG*NJ, 256, 0, stream>>>(inp, wi, wrec, brec, h0, hs, Hhi, Hlo, flags);
  out_gemm<<<(Bn*Tn)/64, 256, 0, stream>>>(hs, wo, out);
}